// Round 2
// baseline (93.177 us; speedup 1.0000x reference)
//
#include <hip/hip_runtime.h>

typedef float v2f __attribute__((ext_vector_type(2)));

#define BB 8            // batches
#define NN 8192         // points per set
#define BLOCK 256
#define QPT 4                    // queries per thread
#define QPB (BLOCK * QPT)        // 1024 queries per block
#define QB (NN / QPB)            // 8 query-blocks per (dir, b)
#define TQ (2 * BB * NN)         // 131072 total queries

// Two reference points, pre-transformed: d = xx + (yy + x0*(-2y0) + x1*(-2y1) + x2*(-2y2))
// packed as float2 lanes (ref 2j in .x, ref 2j+1 in .y) so the inner loop is
// 3 v_pk_fma_f32 + 1 v_min3_f32 per (query, ref-pair) = 2 VALU instrs/pair.
struct __align__(16) RefPair {
  v2f y0, y1, y2, yy;
};

template <int CHUNK>
__global__ __launch_bounds__(BLOCK, 8) void chamfer_partial(
    const float* __restrict__ preds, const float* __restrict__ gts,
    float* __restrict__ partial, int R) {
  constexpr int NPAIR = CHUNK / 2;
  __shared__ RefPair lref[NPAIR];

  int bi = blockIdx.x;
  int r = bi % R;
  int qb = (bi / R) % QB;
  int b = (bi / (R * QB)) % BB;
  int dir = bi / (R * QB * BB);

  // dir 0: queries = preds, refs = gts  (loss_1-style: per-pred nearest gt)
  // dir 1: queries = gts, refs = preds
  const float* qry = (dir == 0) ? preds : gts;
  const float* ref = (dir == 0) ? gts : preds;

  // ---- stage transformed ref pairs into LDS ----
  const float* rbase = ref + ((size_t)b * NN + (size_t)r * CHUNK) * 3;
  for (int j = threadIdx.x; j < NPAIR; j += BLOCK) {
    float a0 = rbase[j * 6 + 0], a1 = rbase[j * 6 + 1], a2 = rbase[j * 6 + 2];
    float c0 = rbase[j * 6 + 3], c1 = rbase[j * 6 + 4], c2 = rbase[j * 6 + 5];
    RefPair rp;
    rp.y0 = v2f{-2.f * a0, -2.f * c0};
    rp.y1 = v2f{-2.f * a1, -2.f * c1};
    rp.y2 = v2f{-2.f * a2, -2.f * c2};
    rp.yy = v2f{a0 * a0 + a1 * a1 + a2 * a2, c0 * c0 + c1 * c1 + c2 * c2};
    lref[j] = rp;
  }
  __syncthreads();

  // ---- this thread's 4 query points ----
  int q0 = qb * QPB + threadIdx.x * QPT;
  const float* qbase = qry + ((size_t)b * NN + q0) * 3;
  float x0[QPT], x1[QPT], x2[QPT], xx[QPT], mn[QPT];
#pragma unroll
  for (int k = 0; k < QPT; ++k) {
    x0[k] = qbase[k * 3 + 0];
    x1[k] = qbase[k * 3 + 1];
    x2[k] = qbase[k * 3 + 2];
    xx[k] = x0[k] * x0[k] + x1[k] * x1[k] + x2[k] * x2[k];
    mn[k] = 3.4e38f;
  }

  // ---- inner loop: per ref-pair per query: 3 pk_fma + 1 min3 ----
#pragma unroll 2
  for (int j = 0; j < NPAIR; ++j) {
    RefPair rp = lref[j];  // uniform broadcast read, conflict-free
#pragma unroll
    for (int k = 0; k < QPT; ++k) {
      v2f t = rp.yy;
      t = v2f{x0[k], x0[k]} * rp.y0 + t;  // v_pk_fma_f32
      t = v2f{x1[k], x1[k]} * rp.y1 + t;
      t = v2f{x2[k], x2[k]} * rp.y2 + t;
      mn[k] = fminf(mn[k], fminf(t.x, t.y));  // v_min3_f32
    }
  }

  // ---- write partial mins (xx folded; constant across R so min-safe) ----
  size_t gq = ((size_t)dir * BB + b) * NN + q0;
  float* out = partial + (size_t)r * TQ + gq;
  float4 res = make_float4(mn[0] + xx[0], mn[1] + xx[1], mn[2] + xx[2],
                           mn[3] + xx[3]);
  *(float4*)out = res;
}

// K2: per query, min over R slices; deterministic block-tree sum.
__global__ __launch_bounds__(BLOCK) void chamfer_reduce(
    const float* __restrict__ partial, float* __restrict__ bsums, int R) {
  int q = blockIdx.x * BLOCK + threadIdx.x;
  float m = 3.4e38f;
  for (int r = 0; r < R; ++r) m = fminf(m, partial[(size_t)r * TQ + q]);
  __shared__ float s[BLOCK];
  s[threadIdx.x] = m;
  __syncthreads();
  for (int o = BLOCK / 2; o > 0; o >>= 1) {
    if (threadIdx.x < o) s[threadIdx.x] += s[threadIdx.x + o];
    __syncthreads();
  }
  if (threadIdx.x == 0) bsums[blockIdx.x] = s[0];
}

// K3: deterministic single-block final sum.
__global__ __launch_bounds__(BLOCK) void chamfer_final(
    const float* __restrict__ bsums, float* __restrict__ out, int n) {
  float v = 0.f;
  for (int i = threadIdx.x; i < n; i += BLOCK) v += bsums[i];
  __shared__ float s[BLOCK];
  s[threadIdx.x] = v;
  __syncthreads();
  for (int o = BLOCK / 2; o > 0; o >>= 1) {
    if (threadIdx.x < o) s[threadIdx.x] += s[threadIdx.x + o];
    __syncthreads();
  }
  if (threadIdx.x == 0) out[0] = s[0];
}

extern "C" void kernel_launch(void* const* d_in, const int* in_sizes, int n_in,
                              void* d_out, int out_size, void* d_ws,
                              size_t ws_size, hipStream_t stream) {
  const float* preds = (const float*)d_in[0];
  const float* gts = (const float*)d_in[1];
  float* out = (float*)d_out;
  float* partial = (float*)d_ws;

  // pick R (ref-chunk split) by available workspace: need R*TQ*4 + bsums
  int R;
  size_t need16 = (size_t)16 * TQ * 4 + 4096;
  size_t need8 = (size_t)8 * TQ * 4 + 4096;
  size_t need4 = (size_t)4 * TQ * 4 + 4096;
  if (ws_size >= need16)
    R = 16;
  else if (ws_size >= need8)
    R = 8;
  else if (ws_size >= need4)
    R = 4;
  else
    R = 2;

  float* bsums = partial + (size_t)R * TQ;
  int nq_blocks = TQ / BLOCK;  // 512

  int grid1 = 2 * BB * QB * R;
  switch (R) {
    case 16:
      chamfer_partial<NN / 16><<<grid1, BLOCK, 0, stream>>>(preds, gts, partial, R);
      break;
    case 8:
      chamfer_partial<NN / 8><<<grid1, BLOCK, 0, stream>>>(preds, gts, partial, R);
      break;
    case 4:
      chamfer_partial<NN / 4><<<grid1, BLOCK, 0, stream>>>(preds, gts, partial, R);
      break;
    default:
      chamfer_partial<NN / 2><<<grid1, BLOCK, 0, stream>>>(preds, gts, partial, R);
      break;
  }
  chamfer_reduce<<<nq_blocks, BLOCK, 0, stream>>>(partial, bsums, R);
  chamfer_final<<<1, BLOCK, 0, stream>>>(bsums, out, nq_blocks);
}